// Round 3
// baseline (286.532 us; speedup 1.0000x reference)
//
#include <hip/hip_runtime.h>
#include <math.h>

typedef __attribute__((ext_vector_type(8))) short short8;
typedef __attribute__((ext_vector_type(4))) float f32x4;

#define TILE 16
#define IH 256
#define IW 256

// ws byte layout: [0,16384) kc f32[64][64]; [16384,81920) wsA frags ushort;
//                 [81920,114688) wsC frags ushort
#define WSA_OFF 16384
#define WSC_OFF 81920

// LDS layout (bytes):
//   H: [16 ch][1456] (18 rows x 80B + 16B pad; stride 364 words => lg*4*364 % 32 = 16)
//   G: @23296: [256 px][80B = 5 granules; 4 data granules rotated by (px>>4)%5]
//   slow-path YS f32[32][260] overlays @0
#define H_STRIDE 1456
#define G_OFF 23296
#define SMEM_BYTES 43776

__device__ __forceinline__ unsigned short f2bf(float f) {
  unsigned int u = __builtin_bit_cast(unsigned int, f);
  u = (u + 0x7FFFu + ((u >> 16) & 1u)) >> 16;
  return (unsigned short)u;
}
__device__ __forceinline__ float bflo(unsigned int v) {
  return __builtin_bit_cast(float, v << 16);
}
__device__ __forceinline__ float bfhi(unsigned int v) {
  return __builtin_bit_cast(float, v & 0xFFFF0000u);
}

__global__ void edffn_prep(const float* __restrict__ fftf,
                           const float* __restrict__ w_in,
                           const float* __restrict__ w_out,
                           float* __restrict__ ws) {
  int blk = blockIdx.x, t = threadIdx.x;
  if (blk < 64) {
    // kc = irfft2 of the (real, symmetric) full-spectrum multiplier
    int a = t >> 3, bb = t & 7;
    const float c0 = 0.70710678118654752f;
    const float ctab[8] = {1.f, c0, 0.f, -c0, -1.f, -c0, 0.f, c0};
    const float* F = fftf + blk * 40;  // [8][5]
    float acc = 0.f;
    for (int k1 = 0; k1 < 8; ++k1)
      for (int k2 = 0; k2 < 8; ++k2) {
        float f = (k2 <= 4) ? F[k1 * 5 + k2] : F[((8 - k1) & 7) * 5 + (8 - k2)];
        acc += f * ctab[(k1 * a + k2 * bb) & 7];
      }
    ws[blk * 64 + t] = acc * (1.f / 64.f);
  } else if (blk < 128) {
    // w_in A-fragments: [chunk q=0..15][s=0,1][ks=0,1][lane][8]
    int b2 = blk - 64;
    int q = b2 >> 2, s = (b2 >> 1) & 1, ks = b2 & 1;
    int row = (s ? 256 : 0) + q * 16 + (t & 15);
    unsigned short* dst =
        (unsigned short*)((unsigned char*)ws + WSA_OFF) + (((q * 2 + s) * 2 + ks) * 64 + t) * 8;
    for (int j = 0; j < 8; ++j) {
      int k = ks * 32 + (t >> 4) * 8 + j;
      dst[j] = f2bf(w_in[row * 64 + k]);
    }
  } else {
    // w_out A-fragments: [pair p=0..7][mtile=0..3][lane][8]
    int b3 = blk - 128;
    int p = b3 >> 2, mt = b3 & 3;
    int row = mt * 16 + (t & 15);
    unsigned short* dst =
        (unsigned short*)((unsigned char*)ws + WSC_OFF) + ((p * 4 + mt) * 64 + t) * 8;
    for (int j = 0; j < 8; ++j) {
      int k = p * 32 + (t >> 4) * 8 + j;
      dst[j] = f2bf(w_out[row * 256 + k]);
    }
  }
}

__global__ __launch_bounds__(256, 3) void edffn_main(
    const float* __restrict__ x, const float* __restrict__ b_in,
    const float* __restrict__ w_dw, const float* __restrict__ b_dw,
    const float* __restrict__ b_out, const float* __restrict__ ws,
    float* __restrict__ out) {
  __shared__ __align__(16) unsigned char smem[SMEM_BYTES];
  __shared__ int s_flag;
  const int t = threadIdx.x;
  const int lane = t & 63, wave = t >> 6;
  const int l15 = lane & 15, lg = lane >> 4;
  const int gx0 = blockIdx.x * TILE, gy0 = blockIdx.y * TILE;
  const int b = blockIdx.z;
  const unsigned short* wsA = (const unsigned short*)((const unsigned char*)ws + WSA_OFF);
  const unsigned short* wsC = (const unsigned short*)((const unsigned char*)ws + WSC_OFF);

  // ---- stage-A B-fragments (x halo, bf16) held in registers across all chunks ----
  short8 xf[6][2];
  int haddr[6], hval[6], hinb[6];
  const float* xb = x + (size_t)b * 64 * 65536;
#pragma unroll
  for (int i = 0; i < 6; ++i) {
    int nt = wave + 4 * i;  // wave0: 0,4,..,20 ; waves1-3: last invalid
    int n = nt * 16 + l15;
    int hy = n / 18;
    int hx = n - hy * 18;
    int gy = gy0 + hy - 1, gx = gx0 + hx - 1;
    int vnt = (nt < 21) & (n < 324);
    int inb = vnt & (gy >= 0) & (gy < IH) & (gx >= 0) & (gx < IW);
    haddr[i] = hy * 80 + hx * 4;
    hval[i] = vnt;
    hinb[i] = inb;
    int gyc = min(max(gy, 0), IH - 1), gxc = min(max(gx, 0), IW - 1);
    const float* xp = xb + (size_t)gyc * IW + gxc;
#pragma unroll
    for (int ks = 0; ks < 2; ++ks) {
#pragma unroll
      for (int j = 0; j < 8; ++j) {
        int k = ks * 32 + lg * 8 + j;
        unsigned short bf = f2bf(xp[(size_t)k * 65536]);
        xf[i][ks][j] = (short)(inb ? bf : (unsigned short)0);
      }
    }
  }

  f32x4 accY[16];
#pragma unroll
  for (int i = 0; i < 16; ++i) accY[i] = (f32x4){0.f, 0.f, 0.f, 0.f};

  const int cp_dw = t >> 4, oy_dw = t & 15;
  const int oy5 = oy_dw % 5;  // G granule-rotation key for writes

  for (int q = 0; q < 16; ++q) {
    // ---- stage A: H(32 gated-ch x 324 px) via MFMA ----
    short8 af[2][2];
#pragma unroll
    for (int s = 0; s < 2; ++s)
#pragma unroll
      for (int ks = 0; ks < 2; ++ks)
        af[s][ks] = *(const short8*)(wsA + (((q * 2 + s) * 2 + ks) * 64 + lane) * 8);
    float bin[2][4];
#pragma unroll
    for (int s = 0; s < 2; ++s)
#pragma unroll
      for (int r = 0; r < 4; ++r) bin[s][r] = b_in[(s ? 256 : 0) + q * 16 + lg * 4 + r];

#pragma unroll
    for (int i = 0; i < 6; ++i) {
      if (wave + 4 * i < 21) {  // wave-uniform
        f32x4 acc0 = {0.f, 0.f, 0.f, 0.f}, acc1 = {0.f, 0.f, 0.f, 0.f};
        acc0 = __builtin_amdgcn_mfma_f32_16x16x32_bf16(af[0][0], xf[i][0], acc0, 0, 0, 0);
        acc0 = __builtin_amdgcn_mfma_f32_16x16x32_bf16(af[0][1], xf[i][1], acc0, 0, 0, 0);
        acc1 = __builtin_amdgcn_mfma_f32_16x16x32_bf16(af[1][0], xf[i][0], acc1, 0, 0, 0);
        acc1 = __builtin_amdgcn_mfma_f32_16x16x32_bf16(af[1][1], xf[i][1], acc1, 0, 0, 0);
        if (hval[i]) {  // per-lane mask on writes only (MFMA stays convergent)
#pragma unroll
          for (int r = 0; r < 4; ++r) {
            float v0 = acc0[r] + bin[0][r];
            float v1 = acc1[r] + bin[1][r];
            unsigned int pk;
            asm("v_cvt_pk_bf16_f32 %0, %1, %2" : "=v"(pk) : "v"(v0), "v"(v1));
            pk = hinb[i] ? pk : 0u;  // SAME pad: h=0 outside image
            *(unsigned int*)(smem + (lg * 4 + r) * H_STRIDE + haddr[i]) = pk;
          }
        }
      }
    }
    __syncthreads();

    // ---- dwconv 3x3 + exact GELU gate (thread = (c', oy), row-wise) ----
    {
      const int cp = cp_dw, oy = oy_dw;
      const int cg1 = q * 16 + cp, cg2 = 256 + q * 16 + cp;
      float wd1[9], wd2[9];
#pragma unroll
      for (int u = 0; u < 9; ++u) {
        wd1[u] = w_dw[cg1 * 9 + u];
        wd2[u] = w_dw[cg2 * 9 + u];
      }
      float a1[16], a2[16];
      const float bd1 = b_dw[cg1], bd2 = b_dw[cg2];
#pragma unroll
      for (int ox = 0; ox < 16; ++ox) {
        a1[ox] = bd1;
        a2[ox] = bd2;
      }
#pragma unroll
      for (int dy = 0; dy < 3; ++dy) {
        const uint4* rp = (const uint4*)(smem + cp * H_STRIDE + (oy + dy) * 80);
        uint4 r0 = rp[0], r1v = rp[1], r2v = rp[2], r3v = rp[3];
        uint2 r4 = ((const uint2*)rp)[8];
        float e1[18], e2[18];
#define UNP(ii, vv)                \
  {                                \
    unsigned int v_ = (vv);        \
    e1[ii] = bflo(v_);             \
    e2[ii] = bfhi(v_);             \
  }
        UNP(0, r0.x) UNP(1, r0.y) UNP(2, r0.z) UNP(3, r0.w)
        UNP(4, r1v.x) UNP(5, r1v.y) UNP(6, r1v.z) UNP(7, r1v.w)
        UNP(8, r2v.x) UNP(9, r2v.y) UNP(10, r2v.z) UNP(11, r2v.w)
        UNP(12, r3v.x) UNP(13, r3v.y) UNP(14, r3v.z) UNP(15, r3v.w)
        UNP(16, r4.x) UNP(17, r4.y)
#undef UNP
#pragma unroll
        for (int ox = 0; ox < 16; ++ox) {
#pragma unroll
          for (int dx = 0; dx < 3; ++dx) {
            a1[ox] = fmaf(wd1[dy * 3 + dx], e1[ox + dx], a1[ox]);
            a2[ox] = fmaf(wd2[dy * 3 + dx], e2[ox + dx], a2[ox]);
          }
        }
      }
      const int c2 = (q & 1) * 16 + cp;
      int gi = (c2 >> 3) + oy5;
      if (gi >= 5) gi -= 5;  // granule-rotated column slot for this thread
      unsigned short* G = (unsigned short*)(smem + G_OFF);
      unsigned short* Gp = G + gi * 8 + (c2 & 7) + oy * 16 * 40;
#pragma unroll
      for (int ox = 0; ox < 16; ++ox) {
        float u = a1[ox];
        float z = u * 0.70710678118654752f;
        float z2 = z * z;
        float erfv;
        if (z2 > 0.16f) {  // |z|>0.4: exact fallback (not taken for this data)
          erfv = erff(z);
        } else {  // 5-term odd Taylor, |err|<3e-8 on |z|<=0.4
          float p = fmaf(z2, 1.f / 216.f, -1.f / 42.f);
          p = fmaf(z2, p, 1.f / 10.f);
          p = fmaf(z2, p, -1.f / 3.f);
          p = fmaf(z2, p, 1.f);
          erfv = 1.12837916709551257f * z * p;
        }
        float g = 0.5f * u * (1.f + erfv) * a2[ox];
        Gp[ox * 40] = f2bf(g);
      }
    }
    __syncthreads();

    // ---- stage C every 2 chunks: y += w_out[:,32] @ G ----
    if (q & 1) {
      const int p = q >> 1;
      short8 cf = *(const short8*)(wsC + ((p * 4 + wave) * 64 + lane) * 8);
      const unsigned short* G = (const unsigned short*)(smem + G_OFF);
#pragma unroll
      for (int nt = 0; nt < 16; ++nt) {
        int g = lg + (nt % 5);
        if (g >= 5) g -= 5;  // reader-side granule rotation (nt uniform per instr)
        int n = nt * 16 + l15;
        short8 bf = *(const short8*)(G + n * 40 + g * 8);
        accY[nt] = __builtin_amdgcn_mfma_f32_16x16x32_bf16(cf, bf, accY[nt], 0, 0, 0);
      }
    }
  }

  // ---- epilogue ----
  f32x4 bo;
#pragma unroll
  for (int r = 0; r < 4; ++r) bo[r] = b_out[wave * 16 + lg * 4 + r];
#pragma unroll
  for (int nt = 0; nt < 16; ++nt)
#pragma unroll
    for (int r = 0; r < 4; ++r) accY[nt][r] += bo[r];

  if (t == 0) s_flag = 1;
  __syncthreads();
  {
    int ok = 1;
    const float* kc = ws;
#pragma unroll
    for (int j = 0; j < 16; ++j) {
      int idx = t * 16 + j;
      float e = ((idx & 63) == 0) ? 1.f : 0.f;
      ok &= (fabsf(kc[idx] - e) <= 1e-5f) ? 1 : 0;
    }
    if (!ok) s_flag = 0;
  }
  __syncthreads();

  const int o = wave * 16 + lg * 4;
  if (s_flag) {  // identity spectral filter: direct store
#pragma unroll
    for (int nt = 0; nt < 16; ++nt) {
      float* op = out + (((size_t)(b * 64 + o)) * IH + gy0 + nt) * IW + gx0 + l15;
#pragma unroll
      for (int r = 0; r < 4; ++r) op[(size_t)r * IH * IW] = accY[nt][r];
    }
    return;
  }

  // general path: per-patch circular convolution with kc (correct for any filter)
  float* YS = (float*)smem;  // [32][260]
  for (int half = 0; half < 2; ++half) {
    __syncthreads();
    if ((wave >> 1) == half) {
      int c32 = (wave & 1) * 16 + lg * 4;
#pragma unroll
      for (int nt = 0; nt < 16; ++nt)
#pragma unroll
        for (int r = 0; r < 4; ++r) YS[(c32 + r) * 260 + nt * 16 + l15] = accY[nt][r];
    }
    __syncthreads();
    if (t < 128) {
      int o32 = t >> 2, oo = half * 32 + o32, qd = t & 3;
      const float* kp = ws + oo * 64;
      int py0 = (qd >> 1) * 8, px0 = (qd & 1) * 8;
      const float* row = YS + o32 * 260;
      for (int i = 0; i < 8; ++i)
        for (int j = 0; j < 8; ++j) {
          float acc = 0.f;
          for (int a_ = 0; a_ < 8; ++a_)
            for (int b_ = 0; b_ < 8; ++b_)
              acc += kp[a_ * 8 + b_] *
                     row[(py0 + ((i - a_) & 7)) * 16 + px0 + ((j - b_) & 7)];
          out[(((size_t)(b * 64 + oo)) * IH + gy0 + py0 + i) * IW + gx0 + px0 + j] = acc;
        }
    }
  }
}

extern "C" void kernel_launch(void* const* d_in, const int* in_sizes, int n_in,
                              void* d_out, int out_size, void* d_ws, size_t ws_size,
                              hipStream_t stream) {
  const float* x = (const float*)d_in[0];
  const float* w_in = (const float*)d_in[1];
  const float* b_in = (const float*)d_in[2];
  const float* w_dw = (const float*)d_in[3];
  const float* b_dw = (const float*)d_in[4];
  const float* w_out = (const float*)d_in[5];
  const float* b_out = (const float*)d_in[6];
  const float* fftf = (const float*)d_in[7];
  float* out = (float*)d_out;
  float* ws = (float*)d_ws;

  edffn_prep<<<160, 64, 0, stream>>>(fftf, w_in, w_out, ws);
  dim3 grid(IW / TILE, IH / TILE, 4);
  edffn_main<<<grid, 256, 0, stream>>>(x, b_in, w_dw, b_dw, b_out, ws, out);
}

// Round 4
// 169.079 us; speedup vs baseline: 1.6947x; 1.6947x over previous
//
#include <hip/hip_runtime.h>
#include <math.h>

typedef __attribute__((ext_vector_type(8))) short short8;
typedef __attribute__((ext_vector_type(4))) float f32x4;
typedef __attribute__((ext_vector_type(2))) float f32x2;

#define TILE 16
#define IH 256
#define IW 256

// ws byte layout: [0,16384) kc f32[64][64]; [16384,81920) wsA frags ushort;
//                 [81920,114688) wsC frags ushort
#define WSA_OFF 16384
#define WSC_OFF 81920

// LDS layout (bytes):
//   H: [16 ch][1456] (18 rows x 80B + 16B pad; stride 364 words => lg*4*364 % 32 = 16)
//   G: @23296: [256 px][80B = 5 granules; 4 data granules rotated by (px>>4)%5]
//   slow-path YS f32[32][260] overlays @0
#define H_STRIDE 1456
#define G_OFF 23296
#define SMEM_BYTES 43776

__device__ __forceinline__ unsigned short f2bf(float f) {
  unsigned int u = __builtin_bit_cast(unsigned int, f);
  u = (u + 0x7FFFu + ((u >> 16) & 1u)) >> 16;
  return (unsigned short)u;
}
__device__ __forceinline__ float bflo(unsigned int v) {
  return __builtin_bit_cast(float, v << 16);
}
__device__ __forceinline__ float bfhi(unsigned int v) {
  return __builtin_bit_cast(float, v & 0xFFFF0000u);
}

__global__ void edffn_prep(const float* __restrict__ fftf,
                           const float* __restrict__ w_in,
                           const float* __restrict__ w_out,
                           float* __restrict__ ws) {
  int blk = blockIdx.x, t = threadIdx.x;
  if (blk < 64) {
    // kc = irfft2 of the (real, symmetric) full-spectrum multiplier
    int a = t >> 3, bb = t & 7;
    const float c0 = 0.70710678118654752f;
    const float ctab[8] = {1.f, c0, 0.f, -c0, -1.f, -c0, 0.f, c0};
    const float* F = fftf + blk * 40;  // [8][5]
    float acc = 0.f;
    for (int k1 = 0; k1 < 8; ++k1)
      for (int k2 = 0; k2 < 8; ++k2) {
        float f = (k2 <= 4) ? F[k1 * 5 + k2] : F[((8 - k1) & 7) * 5 + (8 - k2)];
        acc += f * ctab[(k1 * a + k2 * bb) & 7];
      }
    ws[blk * 64 + t] = acc * (1.f / 64.f);
  } else if (blk < 128) {
    // w_in A-fragments: [chunk q=0..15][s=0,1][ks=0,1][lane][8]
    int b2 = blk - 64;
    int q = b2 >> 2, s = (b2 >> 1) & 1, ks = b2 & 1;
    int row = (s ? 256 : 0) + q * 16 + (t & 15);
    unsigned short* dst =
        (unsigned short*)((unsigned char*)ws + WSA_OFF) + (((q * 2 + s) * 2 + ks) * 64 + t) * 8;
    for (int j = 0; j < 8; ++j) {
      int k = ks * 32 + (t >> 4) * 8 + j;
      dst[j] = f2bf(w_in[row * 64 + k]);
    }
  } else {
    // w_out A-fragments: [pair p=0..7][mtile=0..3][lane][8]
    int b3 = blk - 128;
    int p = b3 >> 2, mt = b3 & 3;
    int row = mt * 16 + (t & 15);
    unsigned short* dst =
        (unsigned short*)((unsigned char*)ws + WSC_OFF) + ((p * 4 + mt) * 64 + t) * 8;
    for (int j = 0; j < 8; ++j) {
      int k = p * 32 + (t >> 4) * 8 + j;
      dst[j] = f2bf(w_out[row * 256 + k]);
    }
  }
}

__global__ __launch_bounds__(256, 2) void edffn_main(
    const float* __restrict__ x, const float* __restrict__ b_in,
    const float* __restrict__ w_dw, const float* __restrict__ b_dw,
    const float* __restrict__ b_out, const float* __restrict__ ws,
    float* __restrict__ out) {
  __shared__ __align__(16) unsigned char smem[SMEM_BYTES];
  __shared__ int s_flag;
  const int t = threadIdx.x;
  const int lane = t & 63, wave = t >> 6;
  const int l15 = lane & 15, lg = lane >> 4;
  const int gx0 = blockIdx.x * TILE, gy0 = blockIdx.y * TILE;
  const int b = blockIdx.z;
  const unsigned short* wsA = (const unsigned short*)((const unsigned char*)ws + WSA_OFF);
  const unsigned short* wsC = (const unsigned short*)((const unsigned char*)ws + WSC_OFF);

  // ---- stage-A B-fragments (x halo, bf16) held in registers across all chunks ----
  short8 xf[6][2];
  int haddr[6], hval[6], hinb[6];
  const float* xb = x + (size_t)b * 64 * 65536;
#pragma unroll
  for (int i = 0; i < 6; ++i) {
    int nt = wave + 4 * i;  // wave0: 0,4,..,20 ; waves1-3: last invalid
    int n = nt * 16 + l15;
    int hy = n / 18;
    int hx = n - hy * 18;
    int gy = gy0 + hy - 1, gx = gx0 + hx - 1;
    int vnt = (nt < 21) & (n < 324);
    int inb = vnt & (gy >= 0) & (gy < IH) & (gx >= 0) & (gx < IW);
    haddr[i] = hy * 80 + hx * 4;
    hval[i] = vnt;
    hinb[i] = inb;
    int gyc = min(max(gy, 0), IH - 1), gxc = min(max(gx, 0), IW - 1);
    const float* xp = xb + (size_t)gyc * IW + gxc;
#pragma unroll
    for (int ks = 0; ks < 2; ++ks) {
#pragma unroll
      for (int j = 0; j < 8; ++j) {
        int k = ks * 32 + lg * 8 + j;
        unsigned short bf = f2bf(xp[(size_t)k * 65536]);
        xf[i][ks][j] = (short)(inb ? bf : (unsigned short)0);
      }
    }
  }

  f32x4 accY[16];
#pragma unroll
  for (int i = 0; i < 16; ++i) accY[i] = (f32x4){0.f, 0.f, 0.f, 0.f};

  const int cp_dw = t >> 4, oy_dw = t & 15;
  const int oy5 = oy_dw % 5;  // G granule-rotation key for writes

  for (int q = 0; q < 16; ++q) {
    // ---- stage A: H(32 gated-ch x 324 px) via MFMA ----
    short8 af[2][2];
#pragma unroll
    for (int s = 0; s < 2; ++s)
#pragma unroll
      for (int ks = 0; ks < 2; ++ks)
        af[s][ks] = *(const short8*)(wsA + (((q * 2 + s) * 2 + ks) * 64 + lane) * 8);
    float bin[2][4];
#pragma unroll
    for (int s = 0; s < 2; ++s)
#pragma unroll
      for (int r = 0; r < 4; ++r) bin[s][r] = b_in[(s ? 256 : 0) + q * 16 + lg * 4 + r];

#pragma unroll
    for (int i = 0; i < 6; ++i) {
      if (wave + 4 * i < 21) {  // wave-uniform
        f32x4 acc0 = {0.f, 0.f, 0.f, 0.f}, acc1 = {0.f, 0.f, 0.f, 0.f};
        acc0 = __builtin_amdgcn_mfma_f32_16x16x32_bf16(af[0][0], xf[i][0], acc0, 0, 0, 0);
        acc0 = __builtin_amdgcn_mfma_f32_16x16x32_bf16(af[0][1], xf[i][1], acc0, 0, 0, 0);
        acc1 = __builtin_amdgcn_mfma_f32_16x16x32_bf16(af[1][0], xf[i][0], acc1, 0, 0, 0);
        acc1 = __builtin_amdgcn_mfma_f32_16x16x32_bf16(af[1][1], xf[i][1], acc1, 0, 0, 0);
        if (hval[i]) {  // per-lane mask on writes only (MFMA stays convergent)
#pragma unroll
          for (int r = 0; r < 4; ++r) {
            float v0 = acc0[r] + bin[0][r];
            float v1 = acc1[r] + bin[1][r];
            unsigned int pk;
            asm("v_cvt_pk_bf16_f32 %0, %1, %2" : "=v"(pk) : "v"(v0), "v"(v1));
            pk = hinb[i] ? pk : 0u;  // SAME pad: h=0 outside image
            *(unsigned int*)(smem + (lg * 4 + r) * H_STRIDE + haddr[i]) = pk;
          }
        }
      }
    }
    __syncthreads();

    // ---- dwconv 3x3 + exact GELU gate (thread = (c', oy), row-wise, pk-f32 math) ----
    {
      const int cp = cp_dw, oy = oy_dw;
      const int cg1 = q * 16 + cp, cg2 = 256 + q * 16 + cp;
      f32x2 wd[9];
#pragma unroll
      for (int u = 0; u < 9; ++u) wd[u] = (f32x2){w_dw[cg1 * 9 + u], w_dw[cg2 * 9 + u]};
      f32x2 a[16];
      const f32x2 bd = (f32x2){b_dw[cg1], b_dw[cg2]};
#pragma unroll
      for (int ox = 0; ox < 16; ++ox) a[ox] = bd;
#pragma unroll
      for (int dy = 0; dy < 3; ++dy) {
        const uint4* rp = (const uint4*)(smem + cp * H_STRIDE + (oy + dy) * 80);
        uint4 r0 = rp[0], r1v = rp[1], r2v = rp[2], r3v = rp[3];
        uint2 r4 = ((const uint2*)rp)[8];
        f32x2 e[18];
#define UNP(ii, vv)                              \
  {                                              \
    unsigned int v_ = (vv);                      \
    e[ii] = (f32x2){bflo(v_), bfhi(v_)};         \
  }
        UNP(0, r0.x) UNP(1, r0.y) UNP(2, r0.z) UNP(3, r0.w)
        UNP(4, r1v.x) UNP(5, r1v.y) UNP(6, r1v.z) UNP(7, r1v.w)
        UNP(8, r2v.x) UNP(9, r2v.y) UNP(10, r2v.z) UNP(11, r2v.w)
        UNP(12, r3v.x) UNP(13, r3v.y) UNP(14, r3v.z) UNP(15, r3v.w)
        UNP(16, r4.x) UNP(17, r4.y)
#undef UNP
#pragma unroll
        for (int ox = 0; ox < 16; ++ox) {
#pragma unroll
          for (int dx = 0; dx < 3; ++dx)
            a[ox] = __builtin_elementwise_fma(wd[dy * 3 + dx], e[ox + dx], a[ox]);
        }
      }
      const int c2 = (q & 1) * 16 + cp;
      int gi = (c2 >> 3) + oy5;
      if (gi >= 5) gi -= 5;  // granule-rotated column slot for this thread
      unsigned short* G = (unsigned short*)(smem + G_OFF);
      unsigned short* Gp = G + gi * 8 + (c2 & 7) + oy * 16 * 40;
#pragma unroll
      for (int ox = 0; ox < 16; ++ox) {
        float u = a[ox][0];
        float z = u * 0.70710678118654752f;
        float z2 = z * z;
        float erfv;
        if (z2 > 0.16f) {  // |z|>0.4: exact fallback (not taken for this data)
          erfv = erff(z);
        } else {  // 5-term odd Taylor, |err|<3e-8 on |z|<=0.4
          float p = fmaf(z2, 1.f / 216.f, -1.f / 42.f);
          p = fmaf(z2, p, 1.f / 10.f);
          p = fmaf(z2, p, -1.f / 3.f);
          p = fmaf(z2, p, 1.f);
          erfv = 1.12837916709551257f * z * p;
        }
        float g = 0.5f * u * (1.f + erfv) * a[ox][1];
        Gp[ox * 40] = f2bf(g);
      }
    }
    __syncthreads();

    // ---- stage C every 2 chunks: y += w_out[:,32] @ G ----
    if (q & 1) {
      const int p = q >> 1;
      short8 cf = *(const short8*)(wsC + ((p * 4 + wave) * 64 + lane) * 8);
      const unsigned short* G = (const unsigned short*)(smem + G_OFF);
#pragma unroll
      for (int nt = 0; nt < 16; ++nt) {
        int g = lg + (nt % 5);
        if (g >= 5) g -= 5;  // reader-side granule rotation (nt uniform per instr)
        int n = nt * 16 + l15;
        short8 bf = *(const short8*)(G + n * 40 + g * 8);
        accY[nt] = __builtin_amdgcn_mfma_f32_16x16x32_bf16(cf, bf, accY[nt], 0, 0, 0);
      }
    }
  }

  // ---- epilogue ----
  f32x4 bo;
#pragma unroll
  for (int r = 0; r < 4; ++r) bo[r] = b_out[wave * 16 + lg * 4 + r];
#pragma unroll
  for (int nt = 0; nt < 16; ++nt)
#pragma unroll
    for (int r = 0; r < 4; ++r) accY[nt][r] += bo[r];

  if (t == 0) s_flag = 1;
  __syncthreads();
  {
    int ok = 1;
    const float* kc = ws;
#pragma unroll
    for (int j = 0; j < 16; ++j) {
      int idx = t * 16 + j;
      float e = ((idx & 63) == 0) ? 1.f : 0.f;
      ok &= (fabsf(kc[idx] - e) <= 1e-5f) ? 1 : 0;
    }
    if (!ok) s_flag = 0;
  }
  __syncthreads();

  const int o = wave * 16 + lg * 4;
  if (s_flag) {  // identity spectral filter: direct store
#pragma unroll
    for (int nt = 0; nt < 16; ++nt) {
      float* op = out + (((size_t)(b * 64 + o)) * IH + gy0 + nt) * IW + gx0 + l15;
#pragma unroll
      for (int r = 0; r < 4; ++r) op[(size_t)r * IH * IW] = accY[nt][r];
    }
    return;
  }

  // general path: per-patch circular convolution with kc (correct for any filter)
  float* YS = (float*)smem;  // [32][260]
  for (int half = 0; half < 2; ++half) {
    __syncthreads();
    if ((wave >> 1) == half) {
      int c32 = (wave & 1) * 16 + lg * 4;
#pragma unroll
      for (int nt = 0; nt < 16; ++nt)
#pragma unroll
        for (int r = 0; r < 4; ++r) YS[(c32 + r) * 260 + nt * 16 + l15] = accY[nt][r];
    }
    __syncthreads();
    if (t < 128) {
      int o32 = t >> 2, oo = half * 32 + o32, qd = t & 3;
      const float* kp = ws + oo * 64;
      int py0 = (qd >> 1) * 8, px0 = (qd & 1) * 8;
      const float* row = YS + o32 * 260;
      for (int i = 0; i < 8; ++i)
        for (int j = 0; j < 8; ++j) {
          float acc = 0.f;
          for (int a_ = 0; a_ < 8; ++a_)
            for (int b_ = 0; b_ < 8; ++b_)
              acc += kp[a_ * 8 + b_] *
                     row[(py0 + ((i - a_) & 7)) * 16 + px0 + ((j - b_) & 7)];
          out[(((size_t)(b * 64 + oo)) * IH + gy0 + py0 + i) * IW + gx0 + px0 + j] = acc;
        }
    }
  }
}

extern "C" void kernel_launch(void* const* d_in, const int* in_sizes, int n_in,
                              void* d_out, int out_size, void* d_ws, size_t ws_size,
                              hipStream_t stream) {
  const float* x = (const float*)d_in[0];
  const float* w_in = (const float*)d_in[1];
  const float* b_in = (const float*)d_in[2];
  const float* w_dw = (const float*)d_in[3];
  const float* b_dw = (const float*)d_in[4];
  const float* w_out = (const float*)d_in[5];
  const float* b_out = (const float*)d_in[6];
  const float* fftf = (const float*)d_in[7];
  float* out = (float*)d_out;
  float* ws = (float*)d_ws;

  edffn_prep<<<160, 64, 0, stream>>>(fftf, w_in, w_out, ws);
  dim3 grid(IW / TILE, IH / TILE, 4);
  edffn_main<<<grid, 256, 0, stream>>>(x, b_in, w_dw, b_dw, b_out, ws, out);
}

// Round 5
// 168.187 us; speedup vs baseline: 1.7037x; 1.0053x over previous
//
#include <hip/hip_runtime.h>
#include <math.h>

typedef __attribute__((ext_vector_type(8))) short short8;
typedef __attribute__((ext_vector_type(4))) float f32x4;
typedef __attribute__((ext_vector_type(2))) float f32x2;

#define TILE 16
#define IH 256
#define IW 256

// ws byte layout: [0,16384) kc f32[64][64]; [16384,81920) wsA frags ushort;
//                 [81920,114688) wsC frags ushort
#define WSA_OFF 16384
#define WSC_OFF 81920

// LDS layout (bytes):
//   H: [16 ch][1456] (18 rows x 80B + 16B pad; plane stride 364 words => lg*4 planes ≡ 16 mod 32)
//   G: @23296: [256 px][64B = 4 granules of 16B, XOR-swizzled: gi = (ch>>3) ^ (oy&3)]
//   slow-path YS f32[32][260] (33280 B) overlays @0
#define H_STRIDE 1456
#define G_OFF 23296
#define SMEM_BYTES 39680

__device__ __forceinline__ unsigned short f2bf(float f) {
  unsigned int u = __builtin_bit_cast(unsigned int, f);
  u = (u + 0x7FFFu + ((u >> 16) & 1u)) >> 16;
  return (unsigned short)u;
}
__device__ __forceinline__ float bflo(unsigned int v) {
  return __builtin_bit_cast(float, v << 16);
}
__device__ __forceinline__ float bfhi(unsigned int v) {
  return __builtin_bit_cast(float, v & 0xFFFF0000u);
}

__global__ void edffn_prep(const float* __restrict__ fftf,
                           const float* __restrict__ w_in,
                           const float* __restrict__ w_out,
                           float* __restrict__ ws) {
  int blk = blockIdx.x, t = threadIdx.x;
  if (blk < 64) {
    // kc = irfft2 of the (real, symmetric) full-spectrum multiplier
    int a = t >> 3, bb = t & 7;
    const float c0 = 0.70710678118654752f;
    const float ctab[8] = {1.f, c0, 0.f, -c0, -1.f, -c0, 0.f, c0};
    const float* F = fftf + blk * 40;  // [8][5]
    float acc = 0.f;
    for (int k1 = 0; k1 < 8; ++k1)
      for (int k2 = 0; k2 < 8; ++k2) {
        float f = (k2 <= 4) ? F[k1 * 5 + k2] : F[((8 - k1) & 7) * 5 + (8 - k2)];
        acc += f * ctab[(k1 * a + k2 * bb) & 7];
      }
    ws[blk * 64 + t] = acc * (1.f / 64.f);
  } else if (blk < 128) {
    // w_in A-fragments: [chunk q=0..15][s=0,1][ks=0,1][lane][8]
    int b2 = blk - 64;
    int q = b2 >> 2, s = (b2 >> 1) & 1, ks = b2 & 1;
    int row = (s ? 256 : 0) + q * 16 + (t & 15);
    unsigned short* dst =
        (unsigned short*)((unsigned char*)ws + WSA_OFF) + (((q * 2 + s) * 2 + ks) * 64 + t) * 8;
    for (int j = 0; j < 8; ++j) {
      int k = ks * 32 + (t >> 4) * 8 + j;
      dst[j] = f2bf(w_in[row * 64 + k]);
    }
  } else {
    // w_out A-fragments: [pair p=0..7][mtile=0..3][lane][8]
    int b3 = blk - 128;
    int p = b3 >> 2, mt = b3 & 3;
    int row = mt * 16 + (t & 15);
    unsigned short* dst =
        (unsigned short*)((unsigned char*)ws + WSC_OFF) + ((p * 4 + mt) * 64 + t) * 8;
    for (int j = 0; j < 8; ++j) {
      int k = p * 32 + (t >> 4) * 8 + j;
      dst[j] = f2bf(w_out[row * 256 + k]);
    }
  }
}

__global__ __launch_bounds__(256, 2) void edffn_main(
    const float* __restrict__ x, const float* __restrict__ b_in,
    const float* __restrict__ w_dw, const float* __restrict__ b_dw,
    const float* __restrict__ b_out, const float* __restrict__ ws,
    float* __restrict__ out) {
  __shared__ __align__(16) unsigned char smem[SMEM_BYTES];
  __shared__ int s_flag;
  const int t = threadIdx.x;
  const int lane = t & 63, wave = t >> 6;
  const int l15 = lane & 15, lg = lane >> 4;
  const int gx0 = blockIdx.x * TILE, gy0 = blockIdx.y * TILE;
  const int b = blockIdx.z;
  const unsigned short* wsA = (const unsigned short*)((const unsigned char*)ws + WSA_OFF);
  const unsigned short* wsC = (const unsigned short*)((const unsigned char*)ws + WSC_OFF);

  // ---- stage-A B-fragments (x halo, bf16) held in registers across all chunks ----
  short8 xf[6][2];
  int haddr[6], hval[6], hinb[6];
  const float* xb = x + (size_t)b * 64 * 65536;
#pragma unroll
  for (int i = 0; i < 6; ++i) {
    int nt = wave + 4 * i;  // wave0: 0,4,..,20 ; waves1-3: last invalid
    int n = nt * 16 + l15;
    int hy = n / 18;
    int hx = n - hy * 18;
    int gy = gy0 + hy - 1, gx = gx0 + hx - 1;
    int vnt = (nt < 21) & (n < 324);
    int inb = vnt & (gy >= 0) & (gy < IH) & (gx >= 0) & (gx < IW);
    haddr[i] = hy * 80 + hx * 4;
    hval[i] = vnt;
    hinb[i] = inb;
    int gyc = min(max(gy, 0), IH - 1), gxc = min(max(gx, 0), IW - 1);
    const float* xp = xb + (size_t)gyc * IW + gxc;
#pragma unroll
    for (int ks = 0; ks < 2; ++ks) {
#pragma unroll
      for (int j = 0; j < 8; ++j) {
        int k = ks * 32 + lg * 8 + j;
        unsigned short bf = f2bf(xp[(size_t)k * 65536]);
        xf[i][ks][j] = (short)(inb ? bf : (unsigned short)0);
      }
    }
  }

  f32x4 accY[16];
#pragma unroll
  for (int i = 0; i < 16; ++i) accY[i] = (f32x4){0.f, 0.f, 0.f, 0.f};

  const int cp_dw = t >> 4, oy_dw = t & 15;

  for (int q = 0; q < 16; ++q) {
    // ---- stage A: H(32 gated-ch x 324 px) via MFMA ----
    short8 af[2][2];
#pragma unroll
    for (int s = 0; s < 2; ++s)
#pragma unroll
      for (int ks = 0; ks < 2; ++ks)
        af[s][ks] = *(const short8*)(wsA + (((q * 2 + s) * 2 + ks) * 64 + lane) * 8);
    float bin[2][4];
#pragma unroll
    for (int s = 0; s < 2; ++s)
#pragma unroll
      for (int r = 0; r < 4; ++r) bin[s][r] = b_in[(s ? 256 : 0) + q * 16 + lg * 4 + r];

#pragma unroll
    for (int i = 0; i < 6; ++i) {
      if (wave + 4 * i < 21) {  // wave-uniform
        f32x4 acc0 = {0.f, 0.f, 0.f, 0.f}, acc1 = {0.f, 0.f, 0.f, 0.f};
        acc0 = __builtin_amdgcn_mfma_f32_16x16x32_bf16(af[0][0], xf[i][0], acc0, 0, 0, 0);
        acc0 = __builtin_amdgcn_mfma_f32_16x16x32_bf16(af[0][1], xf[i][1], acc0, 0, 0, 0);
        acc1 = __builtin_amdgcn_mfma_f32_16x16x32_bf16(af[1][0], xf[i][0], acc1, 0, 0, 0);
        acc1 = __builtin_amdgcn_mfma_f32_16x16x32_bf16(af[1][1], xf[i][1], acc1, 0, 0, 0);
        if (hval[i]) {  // per-lane mask on writes only (MFMA stays convergent)
#pragma unroll
          for (int r = 0; r < 4; ++r) {
            float v0 = acc0[r] + bin[0][r];
            float v1 = acc1[r] + bin[1][r];
            unsigned int pk;
            asm("v_cvt_pk_bf16_f32 %0, %1, %2" : "=v"(pk) : "v"(v0), "v"(v1));
            pk = hinb[i] ? pk : 0u;  // SAME pad: h=0 outside image
            *(unsigned int*)(smem + (lg * 4 + r) * H_STRIDE + haddr[i]) = pk;
          }
        }
      }
    }
    __syncthreads();

    // ---- dwconv 3x3 + exact GELU gate (thread = (c', oy), row-wise, pk-f32 math) ----
    {
      const int cp = cp_dw, oy = oy_dw;
      const int cg1 = q * 16 + cp, cg2 = 256 + q * 16 + cp;
      f32x2 wd[9];
#pragma unroll
      for (int u = 0; u < 9; ++u) wd[u] = (f32x2){w_dw[cg1 * 9 + u], w_dw[cg2 * 9 + u]};
      f32x2 a[16];
      const f32x2 bd = (f32x2){b_dw[cg1], b_dw[cg2]};
#pragma unroll
      for (int ox = 0; ox < 16; ++ox) a[ox] = bd;
#pragma unroll
      for (int dy = 0; dy < 3; ++dy) {
        const uint4* rp = (const uint4*)(smem + cp * H_STRIDE + (oy + dy) * 80);
        uint4 r0 = rp[0], r1v = rp[1], r2v = rp[2], r3v = rp[3];
        uint2 r4 = ((const uint2*)rp)[8];
        f32x2 e[18];
#define UNP(ii, vv)                              \
  {                                              \
    unsigned int v_ = (vv);                      \
    e[ii] = (f32x2){bflo(v_), bfhi(v_)};         \
  }
        UNP(0, r0.x) UNP(1, r0.y) UNP(2, r0.z) UNP(3, r0.w)
        UNP(4, r1v.x) UNP(5, r1v.y) UNP(6, r1v.z) UNP(7, r1v.w)
        UNP(8, r2v.x) UNP(9, r2v.y) UNP(10, r2v.z) UNP(11, r2v.w)
        UNP(12, r3v.x) UNP(13, r3v.y) UNP(14, r3v.z) UNP(15, r3v.w)
        UNP(16, r4.x) UNP(17, r4.y)
#undef UNP
#pragma unroll
        for (int ox = 0; ox < 16; ++ox) {
#pragma unroll
          for (int dx = 0; dx < 3; ++dx)
            a[ox] = __builtin_elementwise_fma(wd[dy * 3 + dx], e[ox + dx], a[ox]);
        }
      }
      const int c2 = (q & 1) * 16 + cp;
      const int gi = (c2 >> 3) ^ (oy & 3);  // 16B-granule XOR swizzle (involution)
      unsigned short* G = (unsigned short*)(smem + G_OFF);
      unsigned short* Gp = G + oy * 16 * 32 + gi * 8 + (c2 & 7);
#pragma unroll
      for (int ox = 0; ox < 16; ++ox) {
        float u = a[ox][0];
        float z = u * 0.70710678118654752f;
        float z2 = z * z;
        float erfv;
        if (z2 > 0.16f) {  // |z|>0.4: exact fallback (not taken for this data)
          erfv = erff(z);
        } else {  // 5-term odd Taylor, |err|<3e-8 on |z|<=0.4
          float p = fmaf(z2, 1.f / 216.f, -1.f / 42.f);
          p = fmaf(z2, p, 1.f / 10.f);
          p = fmaf(z2, p, -1.f / 3.f);
          p = fmaf(z2, p, 1.f);
          erfv = 1.12837916709551257f * z * p;
        }
        float g = 0.5f * u * (1.f + erfv) * a[ox][1];
        Gp[ox * 32] = f2bf(g);
      }
    }
    __syncthreads();

    // ---- stage C every 2 chunks: y += w_out[:,32] @ G ----
    if (q & 1) {
      const int p = q >> 1;
      short8 cf = *(const short8*)(wsC + ((p * 4 + wave) * 64 + lane) * 8);
      const unsigned short* G = (const unsigned short*)(smem + G_OFF);
#pragma unroll
      for (int nt = 0; nt < 16; ++nt) {
        int g = lg ^ (nt & 3);  // reader-side XOR (nt uniform per instr)
        int n = nt * 16 + l15;
        short8 bf = *(const short8*)(G + n * 32 + g * 8);
        accY[nt] = __builtin_amdgcn_mfma_f32_16x16x32_bf16(cf, bf, accY[nt], 0, 0, 0);
      }
    }
  }

  // ---- epilogue ----
  f32x4 bo;
#pragma unroll
  for (int r = 0; r < 4; ++r) bo[r] = b_out[wave * 16 + lg * 4 + r];
#pragma unroll
  for (int nt = 0; nt < 16; ++nt)
#pragma unroll
    for (int r = 0; r < 4; ++r) accY[nt][r] += bo[r];

  if (t == 0) s_flag = 1;
  __syncthreads();
  {
    int ok = 1;
    const float* kc = ws;
#pragma unroll
    for (int j = 0; j < 16; ++j) {
      int idx = t * 16 + j;
      float e = ((idx & 63) == 0) ? 1.f : 0.f;
      ok &= (fabsf(kc[idx] - e) <= 1e-5f) ? 1 : 0;
    }
    if (!ok) s_flag = 0;
  }
  __syncthreads();

  const int o = wave * 16 + lg * 4;
  if (s_flag) {  // identity spectral filter: direct store
#pragma unroll
    for (int nt = 0; nt < 16; ++nt) {
      float* op = out + (((size_t)(b * 64 + o)) * IH + gy0 + nt) * IW + gx0 + l15;
#pragma unroll
      for (int r = 0; r < 4; ++r) op[(size_t)r * IH * IW] = accY[nt][r];
    }
    return;
  }

  // general path: per-patch circular convolution with kc (correct for any filter)
  float* YS = (float*)smem;  // [32][260]
  for (int half = 0; half < 2; ++half) {
    __syncthreads();
    if ((wave >> 1) == half) {
      int c32 = (wave & 1) * 16 + lg * 4;
#pragma unroll
      for (int nt = 0; nt < 16; ++nt)
#pragma unroll
        for (int r = 0; r < 4; ++r) YS[(c32 + r) * 260 + nt * 16 + l15] = accY[nt][r];
    }
    __syncthreads();
    if (t < 128) {
      int o32 = t >> 2, oo = half * 32 + o32, qd = t & 3;
      const float* kp = ws + oo * 64;
      int py0 = (qd >> 1) * 8, px0 = (qd & 1) * 8;
      const float* row = YS + o32 * 260;
      for (int i = 0; i < 8; ++i)
        for (int j = 0; j < 8; ++j) {
          float acc = 0.f;
          for (int a_ = 0; a_ < 8; ++a_)
            for (int b_ = 0; b_ < 8; ++b_)
              acc += kp[a_ * 8 + b_] *
                     row[(py0 + ((i - a_) & 7)) * 16 + px0 + ((j - b_) & 7)];
          out[(((size_t)(b * 64 + oo)) * IH + gy0 + py0 + i) * IW + gx0 + px0 + j] = acc;
        }
    }
  }
}

extern "C" void kernel_launch(void* const* d_in, const int* in_sizes, int n_in,
                              void* d_out, int out_size, void* d_ws, size_t ws_size,
                              hipStream_t stream) {
  const float* x = (const float*)d_in[0];
  const float* w_in = (const float*)d_in[1];
  const float* b_in = (const float*)d_in[2];
  const float* w_dw = (const float*)d_in[3];
  const float* b_dw = (const float*)d_in[4];
  const float* w_out = (const float*)d_in[5];
  const float* b_out = (const float*)d_in[6];
  const float* fftf = (const float*)d_in[7];
  float* out = (float*)d_out;
  float* ws = (float*)d_ws;

  edffn_prep<<<160, 64, 0, stream>>>(fftf, w_in, w_out, ws);
  dim3 grid(IW / TILE, IH / TILE, 4);
  edffn_main<<<grid, 256, 0, stream>>>(x, b_in, w_dw, b_dw, b_out, ws, out);
}